// Round 4
// baseline (314.828 us; speedup 1.0000x reference)
//
#include <hip/hip_runtime.h>

// LightGCN, 3-layer propagation, 200001 nodes, D=64.
// Round 10: SpMM record-staging in LDS. Rounds 0-9 established:
// two-phase bucket CSR build at T_TILE=4096 + line-padded/replicated
// counters + final-layer fusion = 312.8us, with the 3 spmm kernels now
// ~150us combined and latency-epoch-bound (row_ptr -> records ->
// gather serial chain, ~5 epochs/thread at 40% occupancy; only 29%
// VALUBusy, 3.9 TB/s). Fix: per-block (32 rows) cooperative stage of
// the contiguous CSR record range + row_ptr slice into LDS (one
// coalesced epoch), then gathers stream with records read from LDS
// (broadcast, conflict-free). y1/y2/emb epilogue reads hoisted above
// the edge loop in spmm_final to overlap the gather stream.

#define N_NODES 200001
#define NUP1    100001            // NUM_USERS + 1
#define D       64
#define DV      16                // float4/ushort4 per row (init/final)
#define DV8     8                 // uint4 (8 bf16) per row (spmm)
#define CHUNK   512
#define NCHUNK  ((N_NODES + CHUNK - 1) / CHUNK)   // 391
#define T_TILE  4096              // edges per pass1 block
#define EPT     16                // edges per thread in pass1
#define CAP     6144              // bucket capacity (exp ~5115, +14 sigma)
#define REP     2                 // counter replicas (by block parity)
#define HALFCAP (CAP / REP)       // 3072 (exp ~2558, +10 sigma)
#define CNT_STRIDE 16             // ints; one counter per 64B line
#define CNT_TOTAL  (NCHUNK * REP * CNT_STRIDE)   // 12512 ints
#define RPB     32                // rows per spmm block
#define REC_CAP 768               // staged records/block (exp ~320, +25 sigma)

__device__ __forceinline__ unsigned short f2bf(float f) {
  unsigned u = __float_as_uint(f);
  unsigned r = (u + 0x7FFFu + ((u >> 16) & 1u)) >> 16;   // RNE
  return (unsigned short)r;
}
__device__ __forceinline__ float bf2f(unsigned short h) {
  return __uint_as_float(((unsigned)h) << 16);
}
__device__ __forceinline__ float bflo(unsigned u) { return __uint_as_float(u << 16); }
__device__ __forceinline__ float bfhi(unsigned u) { return __uint_as_float(u & 0xFFFF0000u); }

// Build x0 (bf16) from fp32 embeddings; also zero padded bucket counters.
__global__ __launch_bounds__(256) void init_kernel(
    const float4* __restrict__ user_emb,
    const float4* __restrict__ item_emb,
    ushort4* __restrict__ x0,
    int* __restrict__ bucket_cnt) {
  int idx = blockIdx.x * 256 + threadIdx.x;
  if (idx < CNT_TOTAL) bucket_cnt[idx] = 0;
  if (idx >= N_NODES * DV) return;
  int n = idx >> 4;
  int j = idx & 15;
  float4 v = (n < NUP1) ? user_emb[idx]
                        : item_emb[(size_t)(n - 100000) * DV + j];
  x0[idx] = make_ushort4(f2bf(v.x), f2bf(v.y), f2bf(v.z), f2bf(v.w));
}

// Pass 1: multisplit edges into 391 chunk-buckets (private per-block runs).
// Counter for (bucket b, replica r) at bucket_cnt[(b*REP+r)*CNT_STRIDE];
// replica r = blockIdx.x & 1 owns sub-region [b*CAP + r*HALFCAP, ...).
__global__ __launch_bounds__(256) void pass1_bucket(
    const int*   __restrict__ rows,
    const int*   __restrict__ cols,
    const float* __restrict__ vals,
    int*  __restrict__ bucket_cnt,
    int2* __restrict__ bucket_arr,
    int nnz) {
  __shared__ int lcount[NCHUNK];
  __shared__ int lbase[NCHUNK];
  int t = threadIdx.x;
  for (int i = t; i < NCHUNK; i += 256) lcount[i] = 0;
  __syncthreads();
  long base = (long)blockIdx.x * T_TILE;
  int rep = blockIdx.x & (REP - 1);
  int2 pk[EPT];
  int  meta[EPT];
#pragma unroll
  for (int k = 0; k < EPT; ++k) {
    long e = base + t + (long)k * 256;
    if (e < nnz) {
      int r = rows[e];
      int b = r >> 9;                          // chunk bucket (0..390)
      int rank = atomicAdd(&lcount[b], 1);     // LDS atomic
      pk[k] = make_int2(((r & 511) << 18) | cols[e], __float_as_int(vals[e]));
      meta[k] = (rank << 9) | b;               // rank<4096 (12b) | b (9b)
    } else {
      meta[k] = -1;
    }
  }
  __syncthreads();
  for (int b = t; b < NCHUNK; b += 256) {
    int c = lcount[b];
    lbase[b] = (c > 0)
        ? (b * CAP + rep * HALFCAP +
           atomicAdd(&bucket_cnt[(b * REP + rep) * CNT_STRIDE], c))
        : 0;
  }
  __syncthreads();
#pragma unroll
  for (int k = 0; k < EPT; ++k) {
    if (meta[k] >= 0) {
      int b = meta[k] & 511;
      int rank = meta[k] >> 9;
      bucket_arr[lbase[b] + rank] = pk[k];
    }
  }
}

// Parallel exclusive scan of 391 combined chunk counts (one block).
__global__ __launch_bounds__(512) void scan_chunks_kernel(
    const int* __restrict__ cnt, int* __restrict__ off,
    int* __restrict__ row_ptr, int nnz) {
  __shared__ int sh[512];
  int t = threadIdx.x;
  int v = (t < NCHUNK)
      ? cnt[(t * REP + 0) * CNT_STRIDE] + cnt[(t * REP + 1) * CNT_STRIDE]
      : 0;
  sh[t] = v;
  __syncthreads();
  for (int o = 1; o < 512; o <<= 1) {
    int u = (t >= o) ? sh[t - o] : 0;
    __syncthreads();
    sh[t] += u;
    __syncthreads();
  }
  if (t < NCHUNK) off[t] = sh[t] - v;   // exclusive prefix
  if (t == 0) row_ptr[N_NODES] = nnz;
}

// Fused per-chunk: LDS histogram -> LDS scan -> row_ptr write -> scatter
// into final CSR order with LDS cursors. Reads both replica segments.
__global__ __launch_bounds__(256) void build_csr_chunk(
    const int*  __restrict__ bucket_cnt,
    const int2* __restrict__ bucket_arr,
    const int*  __restrict__ chunk_off,
    int*  __restrict__ row_ptr,
    int2* __restrict__ edge_s) {
  __shared__ int lcnt[CHUNK];     // histogram, then cursors
  __shared__ int tsum[256];
  int b = blockIdx.x, t = threadIdx.x;
  lcnt[t] = 0; lcnt[t + 256] = 0;
  __syncthreads();
  int ne0 = bucket_cnt[(b * REP + 0) * CNT_STRIDE];
  int ne1 = bucket_cnt[(b * REP + 1) * CNT_STRIDE];
  const int2* ba = bucket_arr + (size_t)b * CAP;
  for (int i = t; i < ne0; i += 256)
    atomicAdd(&lcnt[ba[i].x >> 18], 1);
  for (int i = t; i < ne1; i += 256)
    atomicAdd(&lcnt[ba[HALFCAP + i].x >> 18], 1);
  __syncthreads();
  int base = t * 2;
  int l0 = lcnt[base], l1 = lcnt[base + 1];
  int s = l0 + l1;
  tsum[t] = s;
  __syncthreads();
  for (int o = 1; o < 256; o <<= 1) {
    int v = (t >= o) ? tsum[t - o] : 0;
    __syncthreads();
    tsum[t] += v;
    __syncthreads();
  }
  int run = tsum[t] - s + chunk_off[b];
  int row0 = b * CHUNK;
  if (row0 + base < N_NODES) row_ptr[row0 + base] = run;
  lcnt[base] = run;
  run += l0;
  if (row0 + base + 1 < N_NODES) row_ptr[row0 + base + 1] = run;
  lcnt[base + 1] = run;
  __syncthreads();
  for (int i = t; i < ne0; i += 256) {
    int2 ed = ba[i];
    int p = atomicAdd(&lcnt[ed.x >> 18], 1);
    edge_s[p] = make_int2(ed.x & 0x3FFFF, ed.y);
  }
  for (int i = t; i < ne1; i += 256) {
    int2 ed = ba[HALFCAP + i];
    int p = atomicAdd(&lcnt[ed.x >> 18], 1);
    edge_s[p] = make_int2(ed.x & 0x3FFFF, ed.y);
  }
}

// ---------- SpMM with LDS record staging ----------
// Block owns RPB=32 consecutive rows; their CSR records are contiguous
// in edge_s. Stage records + row_ptr slice into LDS in one coalesced
// epoch, then stream gathers with records read from LDS (broadcast
// across the 8 lanes of a row-group -> conflict-free).

#define ACCUM(V, XV) {                                    \
    a0 += (V) * bflo((XV).x); a1 += (V) * bfhi((XV).x);   \
    a2 += (V) * bflo((XV).y); a3 += (V) * bfhi((XV).y);   \
    a4 += (V) * bflo((XV).z); a5 += (V) * bfhi((XV).z);   \
    a6 += (V) * bflo((XV).w); a7 += (V) * bfhi((XV).w); }

#define FETCH_LDS(i) lrec[(i)]
#define FETCH_GLB(i) edge_s[sB + (i)]

#define GROUP_LOOP(FETCH)                                           \
  for (int gg = s; gg < e; gg += 8) {                               \
    int2 e0 = FETCH(min(gg + 0, last));                             \
    int2 e1 = FETCH(min(gg + 1, last));                             \
    int2 e2 = FETCH(min(gg + 2, last));                             \
    int2 e3 = FETCH(min(gg + 3, last));                             \
    int2 e4 = FETCH(min(gg + 4, last));                             \
    int2 e5 = FETCH(min(gg + 5, last));                             \
    int2 e6 = FETCH(min(gg + 6, last));                             \
    int2 e7 = FETCH(min(gg + 7, last));                             \
    uint4 g0 = x[(size_t)e0.x * DV8 + j];                           \
    uint4 g1 = x[(size_t)e1.x * DV8 + j];                           \
    uint4 g2 = x[(size_t)e2.x * DV8 + j];                           \
    uint4 g3 = x[(size_t)e3.x * DV8 + j];                           \
    uint4 g4 = x[(size_t)e4.x * DV8 + j];                           \
    uint4 g5 = x[(size_t)e5.x * DV8 + j];                           \
    uint4 g6 = x[(size_t)e6.x * DV8 + j];                           \
    uint4 g7 = x[(size_t)e7.x * DV8 + j];                           \
    float v0 = __int_as_float(e0.y);                                \
    float v1 = (gg + 1 < e) ? __int_as_float(e1.y) : 0.f;           \
    float v2 = (gg + 2 < e) ? __int_as_float(e2.y) : 0.f;           \
    float v3 = (gg + 3 < e) ? __int_as_float(e3.y) : 0.f;           \
    float v4 = (gg + 4 < e) ? __int_as_float(e4.y) : 0.f;           \
    float v5 = (gg + 5 < e) ? __int_as_float(e5.y) : 0.f;           \
    float v6 = (gg + 6 < e) ? __int_as_float(e6.y) : 0.f;           \
    float v7 = (gg + 7 < e) ? __int_as_float(e7.y) : 0.f;           \
    ACCUM(v0, g0); ACCUM(v1, g1); ACCUM(v2, g2); ACCUM(v3, g3);     \
    ACCUM(v4, g4); ACCUM(v5, g5); ACCUM(v6, g6); ACCUM(v7, g7);     \
  }

// Shared prologue: stage, compute s/e (block-relative), no early return
// before __syncthreads.
#define SPMM_PROLOGUE                                               \
  __shared__ int2 lrec[REC_CAP];                                    \
  __shared__ int  lrp[RPB + 1];                                     \
  int t = threadIdx.x;                                              \
  int gt = blockIdx.x * 256 + t;                                    \
  int r0 = blockIdx.x * RPB;                                        \
  int sB = row_ptr[r0];                                             \
  int eB = row_ptr[min(r0 + RPB, N_NODES)];                         \
  int ne = eB - sB;                                                 \
  bool lds_path = (ne <= REC_CAP);                                  \
  if (lds_path)                                                     \
    for (int i = t; i < ne; i += 256) lrec[i] = edge_s[sB + i];     \
  if (t <= RPB) lrp[t] = row_ptr[min(r0 + t, N_NODES)];             \
  __syncthreads();                                                  \
  int r = gt >> 3;                                                  \
  int j = t & 7;                                                    \
  float a0 = 0.f, a1 = 0.f, a2 = 0.f, a3 = 0.f;                     \
  float a4 = 0.f, a5 = 0.f, a6 = 0.f, a7 = 0.f;                     \
  int s = lrp[t >> 3] - sB;                                         \
  int e = lrp[(t >> 3) + 1] - sB;                                   \
  if (r >= N_NODES) { s = 0; e = 0; }                               \
  int last = e - 1;

__global__ __launch_bounds__(256) void spmm_bf16_kernel(
    const int*  __restrict__ row_ptr,
    const int2* __restrict__ edge_s,
    const uint4* __restrict__ x,
    uint4*       __restrict__ y) {
  SPMM_PROLOGUE
  if (lds_path) { GROUP_LOOP(FETCH_LDS) } else { GROUP_LOOP(FETCH_GLB) }
  if (r < N_NODES) {
    uint4 o;
    o.x = ((unsigned)f2bf(a1) << 16) | f2bf(a0);
    o.y = ((unsigned)f2bf(a3) << 16) | f2bf(a2);
    o.z = ((unsigned)f2bf(a5) << 16) | f2bf(a4);
    o.w = ((unsigned)f2bf(a7) << 16) | f2bf(a6);
    y[gt] = o;
  }
}

// Layer-3 SpMM fused with the final average:
// out[rowmap(r)] = 0.25*(emb_fp32 + y1 + y2 + a); y3 never materialized.
// Epilogue row reads hoisted above the edge loop to overlap gathers.
__global__ __launch_bounds__(256) void spmm_final_kernel(
    const int*  __restrict__ row_ptr,
    const int2* __restrict__ edge_s,
    const uint4* __restrict__ x,          // = y2 (gather input)
    const uint4* __restrict__ y1u,
    const float4* __restrict__ user_emb,
    const float4* __restrict__ item_emb,
    float4* __restrict__ out) {
  SPMM_PROLOGUE
  if (gt < DV) out[(size_t)NUP1 * DV + gt] = make_float4(0.f, 0.f, 0.f, 0.f);
  int rr = min(r, N_NODES - 1);
  uint4 w1 = y1u[(size_t)rr * DV8 + j];
  uint4 w2 = x  [(size_t)rr * DV8 + j];    // y2 row (x aliases y2)
  float4 f0, f1;
  if (rr < NUP1) {
    size_t eb = (size_t)rr * DV + 2 * j;
    f0 = user_emb[eb];
    f1 = user_emb[eb + 1];
  } else {
    size_t ib = (size_t)(rr - 100000) * DV + 2 * j;
    f0 = item_emb[ib];
    f1 = item_emb[ib + 1];
  }
  if (lds_path) { GROUP_LOOP(FETCH_LDS) } else { GROUP_LOOP(FETCH_GLB) }
  if (r < N_NODES) {
    int rm = (r < NUP1) ? r : r + 1;
    float4 o0, o1;
    o0.x = 0.25f * (f0.x + bflo(w1.x) + bflo(w2.x) + a0);
    o0.y = 0.25f * (f0.y + bfhi(w1.x) + bfhi(w2.x) + a1);
    o0.z = 0.25f * (f0.z + bflo(w1.y) + bflo(w2.y) + a2);
    o0.w = 0.25f * (f0.w + bfhi(w1.y) + bfhi(w2.y) + a3);
    o1.x = 0.25f * (f1.x + bflo(w1.z) + bflo(w2.z) + a4);
    o1.y = 0.25f * (f1.y + bfhi(w1.z) + bfhi(w2.z) + a5);
    o1.z = 0.25f * (f1.z + bflo(w1.w) + bflo(w2.w) + a6);
    o1.w = 0.25f * (f1.w + bfhi(w1.w) + bfhi(w2.w) + a7);
    out[(size_t)rm * DV + 2 * j]     = o0;
    out[(size_t)rm * DV + 2 * j + 1] = o1;
  }
}

static inline char* align16(char* p) {
  return (char*)(((uintptr_t)p + 15) & ~(uintptr_t)15);
}

extern "C" void kernel_launch(void* const* d_in, const int* in_sizes, int n_in,
                              void* d_out, int out_size, void* d_ws, size_t ws_size,
                              hipStream_t stream) {
  const float* user_emb = (const float*)d_in[0];
  const float* item_emb = (const float*)d_in[1];
  const int*   rows     = (const int*)d_in[2];
  const int*   cols     = (const int*)d_in[3];
  const float* vals     = (const float*)d_in[4];
  const int    nnz      = in_sizes[2];

  const size_t xbytes = (size_t)N_NODES * D * sizeof(unsigned short); // 25.6 MB
  char* p = (char*)d_ws;
  ushort4* x0 = (ushort4*)p;  p += xbytes;
  ushort4* y1 = (ushort4*)p;  p += xbytes;
  ushort4* y2 = (ushort4*)p;  p += xbytes;
  ushort4* y3 = (ushort4*)p;  p += xbytes;  // scratch window for bucket_arr
  // bucket_arr aliases y2+y3 (51.2 MB window; needs 19.2 MB): fully consumed
  // by build_csr_chunk before layer-2 spmm writes y2.
  int2* bucket_arr = (int2*)y2;
  (void)y3;
  p = align16(p);
  int2* edge_s = (int2*)p;    p += (size_t)nnz * sizeof(int2);
  p = align16(p);
  int* row_ptr = (int*)p;     p += (size_t)(N_NODES + 1) * sizeof(int);
  p = align16(p);
  int* chunk_off = (int*)p;   p += (size_t)NCHUNK * sizeof(int);
  p = align16(p);
  int* bucket_cnt = (int*)p;  p += (size_t)CNT_TOTAL * sizeof(int);

  float* out = (float*)d_out;

  const int row_elems = N_NODES * DV;                // 3,200,016
  const int node_grid = (row_elems + 255) / 256;     // 12501
  const int spmm_grid = (N_NODES * DV8 + 255) / 256; // 6251
  const int tile_grid = (nnz + T_TILE - 1) / T_TILE;

  init_kernel<<<node_grid, 256, 0, stream>>>(
      (const float4*)user_emb, (const float4*)item_emb, x0, bucket_cnt);
  pass1_bucket<<<tile_grid, 256, 0, stream>>>(
      rows, cols, vals, bucket_cnt, bucket_arr, nnz);
  scan_chunks_kernel<<<1, 512, 0, stream>>>(bucket_cnt, chunk_off, row_ptr, nnz);
  build_csr_chunk<<<NCHUNK, 256, 0, stream>>>(
      bucket_cnt, bucket_arr, chunk_off, row_ptr, edge_s);

  spmm_bf16_kernel<<<spmm_grid, 256, 0, stream>>>(
      row_ptr, edge_s, (const uint4*)x0, (uint4*)y1);
  spmm_bf16_kernel<<<spmm_grid, 256, 0, stream>>>(
      row_ptr, edge_s, (const uint4*)y1, (uint4*)y2);
  spmm_final_kernel<<<spmm_grid, 256, 0, stream>>>(
      row_ptr, edge_s, (const uint4*)y2, (const uint4*)y1,
      (const float4*)user_emb, (const float4*)item_emb, (float4*)out);
}